// Round 1
// baseline (204.047 us; speedup 1.0000x reference)
//
#include <hip/hip_runtime.h>
#include <hip/hip_fp16.h>

// OTK (optimal-transport kernel attention) for MI355X.
// Pipeline:
//   k0: xT[b][d][n] = fp16(x)            (transpose for k3 B-operand)
//   k1: E[b][h][n][m] = exp(-10*C*pf)    (fp16 MFMA GEMM + fused epilogue)
//   k2: exp-domain Sinkhorn, E register-resident per (b,h) block,
//       writes Pt[b][m][h][n] = P transposed, fp16
//   k3: out[b][m*4+h][d] = Pt @ x        (fp16 MFMA GEMM)
// Identity used: lse_m(K+u+v) = u + lse_m(K+v)  =>  plain Sinkhorn on E=exp(K):
//   eu <- (1/N)/(eu*(E ev));  ev <- 1/(ev*(E^T eu));  P = E*eu*ev

typedef _Float16 h2 __attribute__((ext_vector_type(2)));
typedef _Float16 h8 __attribute__((ext_vector_type(8)));
typedef float f4 __attribute__((ext_vector_type(4)));

#define NB 16
#define NN 2048
#define ND 512
#define NH 4
#define NM 64
#define NITER 30
#define EUSCALE 8.0f   // keeps fp16(eu*EUSCALE) in normal range (eu >= ~1e-5)

static __device__ __forceinline__ float fdot2f(h2 a, h2 b, float c) {
#if __has_builtin(__builtin_amdgcn_fdot2)
  return __builtin_amdgcn_fdot2(a, b, c, false);
#else
  return (float)a[0] * (float)b[0] + (float)a[1] * (float)b[1] + c;
#endif
}

static __device__ __forceinline__ h2 pkrtz(float a, float b) {
  return __builtin_bit_cast(h2, __builtin_amdgcn_cvt_pkrtz(a, b));
}

static __device__ __forceinline__ h8 pack8(float4 a, float4 b) {
  h8 r;
  r[0] = (_Float16)a.x; r[1] = (_Float16)a.y; r[2] = (_Float16)a.z; r[3] = (_Float16)a.w;
  r[4] = (_Float16)b.x; r[5] = (_Float16)b.y; r[6] = (_Float16)b.z; r[7] = (_Float16)b.w;
  return r;
}

static __device__ __forceinline__ float sq4(float4 a) {
  return a.x * a.x + a.y * a.y + a.z * a.z + a.w * a.w;
}

// ---------------------------------------------------------------- k0: x -> xT
// 64x64 tiles through LDS (pad 65 -> 2-way max bank conflict both sides).
__global__ __launch_bounds__(256) void k0_xt(const float* __restrict__ x,
                                             _Float16* __restrict__ xT) {
  __shared__ float tile[64][65];
  const int b = blockIdx.z;
  const int n0 = blockIdx.x * 64;
  const int d0 = blockIdx.y * 64;
  const int t = threadIdx.x;
  const int nr = t >> 2;
  const int ds = (t & 3) * 16;
  const float4* src = (const float4*)(x + ((size_t)(b * NN + n0 + nr) * ND + d0 + ds));
  float4 v0 = src[0], v1 = src[1], v2 = src[2], v3 = src[3];
  float vals[16] = {v0.x, v0.y, v0.z, v0.w, v1.x, v1.y, v1.z, v1.w,
                    v2.x, v2.y, v2.z, v2.w, v3.x, v3.y, v3.z, v3.w};
#pragma unroll
  for (int j = 0; j < 16; ++j) tile[ds + j][nr] = vals[j];
  __syncthreads();
  const int dr = t >> 2;
  const int ns = (t & 3) * 16;
  h8 o0, o1;
#pragma unroll
  for (int j = 0; j < 8; ++j) o0[j] = (_Float16)tile[dr][ns + j];
#pragma unroll
  for (int j = 0; j < 8; ++j) o1[j] = (_Float16)tile[dr][ns + 8 + j];
  _Float16* dst = xT + ((size_t)(b * ND + d0 + dr) * NN + n0 + ns);
  *(h8*)dst = o0;
  *(h8*)(dst + 8) = o1;
}

// ------------------------------------------------------------- k1: build E
// Per block: n-tile of 128 x all 4 heads (256 cols), K=512, fp16 MFMA.
// x2/w2 accumulated during staging (each element staged exactly once).
__global__ __launch_bounds__(512) void k1_buildE(const float* __restrict__ x,
                                                 const float* __restrict__ w,
                                                 _Float16* __restrict__ E) {
  __shared__ _Float16 Ah[128][72];   // +8 pad: balanced banks for b128 reads
  __shared__ _Float16 Bh[256][72];
  __shared__ float x2s[128][4];
  __shared__ float w2s[256][2];
  __shared__ float x2r[128];
  __shared__ float w2r[256];

  const int b = blockIdx.y;
  const int n0 = blockIdx.x * 128;
  const int tid = threadIdx.x;
  const int lane = tid & 63;
  const int wv = tid >> 6;        // 8 waves, 16 n-rows each
  const int lrow = lane & 15;
  const int kq = lane >> 4;

  f4 acc[16];
#pragma unroll
  for (int i = 0; i < 16; ++i) acc[i] = (f4){0.f, 0.f, 0.f, 0.f};

  const int ar = tid >> 2, ac = (tid & 3) * 16;
  const int br = tid >> 1, bc = (tid & 1) * 32;
  const float* xsrc = x + ((size_t)(b * NN + n0 + ar) * ND + ac);
  const float* wsrc = w + ((size_t)br * ND + bc);
  float x2p = 0.f, w2p = 0.f;

  for (int kt = 0; kt < 8; ++kt) {
    {
      const float4* s4 = (const float4*)(xsrc + kt * 64);
      float4 a0 = s4[0], a1 = s4[1], a2 = s4[2], a3 = s4[3];
      x2p += sq4(a0) + sq4(a1) + sq4(a2) + sq4(a3);
      *(h8*)&Ah[ar][ac] = pack8(a0, a1);
      *(h8*)&Ah[ar][ac + 8] = pack8(a2, a3);
    }
    {
      const float4* s4 = (const float4*)(wsrc + kt * 64);
      float4 u0 = s4[0], u1 = s4[1], u2 = s4[2], u3 = s4[3];
      float4 u4 = s4[4], u5 = s4[5], u6 = s4[6], u7 = s4[7];
      w2p += sq4(u0) + sq4(u1) + sq4(u2) + sq4(u3)
           + sq4(u4) + sq4(u5) + sq4(u6) + sq4(u7);
      *(h8*)&Bh[br][bc] = pack8(u0, u1);
      *(h8*)&Bh[br][bc + 8] = pack8(u2, u3);
      *(h8*)&Bh[br][bc + 16] = pack8(u4, u5);
      *(h8*)&Bh[br][bc + 24] = pack8(u6, u7);
    }
    __syncthreads();
#pragma unroll
    for (int s = 0; s < 2; ++s) {
      h8 af = *(const h8*)&Ah[wv * 16 + lrow][s * 32 + kq * 8];
#pragma unroll
      for (int cf = 0; cf < 16; ++cf) {
        h8 bf = *(const h8*)&Bh[cf * 16 + lrow][s * 32 + kq * 8];
        acc[cf] = __builtin_amdgcn_mfma_f32_16x16x32_f16(af, bf, acc[cf], 0, 0, 0);
      }
    }
    __syncthreads();
  }

  x2s[ar][tid & 3] = x2p;
  w2s[br][tid & 1] = w2p;
  __syncthreads();
  if (tid < 128) {
    x2r[tid] = x2s[tid][0] + x2s[tid][1] + x2s[tid][2] + x2s[tid][3];
  } else if (tid < 384) {
    const int r = tid - 128;
    w2r[r] = w2s[r][0] + w2s[r][1];
  }
  __syncthreads();

#pragma unroll
  for (int cf = 0; cf < 16; ++cf) {
    const int mg = cf * 16 + lrow;
    const int hh = mg >> 6;
    const int m = mg & 63;
    const float w2v = w2r[mg];
    const float bm = (float)m * (1.0f / 64.0f);
    _Float16* Eb = E + ((size_t)(b * NH + hh) * NN) * NM;
#pragma unroll
    for (int j = 0; j < 4; ++j) {
      const int nl = wv * 16 + kq * 4 + j;   // C/D: row=(lane>>4)*4+reg
      const int n = n0 + nl;
      const float c2 = x2r[nl] + w2v - 2.0f * acc[cf][j];
      const float Cd = sqrtf(fmaxf(c2, 0.0f));
      const float tt = (float)n * (1.0f / 2048.0f) - bm;
      const float pf = __expf(-100.0f * tt * tt);
      const float Ev = __expf(-10.0f * Cd * pf);   // K = (-C/eps)*pf, eps=0.1
      Eb[(size_t)n * NM + m] = (_Float16)Ev;
    }
  }
}

// ------------------------------------------------------------ k2: Sinkhorn
// One block per (b,h). 256 threads x 8 rows, E fp16 in registers (256 VGPR).
// Per iter: S via v_dot2_f32_f16, T via v_pk_fma_f16 with eu scaled by 8,
// register-halving butterfly (lane l -> col-pair bitrev5(l&31)), LDS combine.
__global__ __launch_bounds__(256, 1) void k2_sinkhorn(const _Float16* __restrict__ E,
                                                      _Float16* __restrict__ Pt) {
  const int bh = blockIdx.x;
  const int b = bh >> 2, h = bh & 3;
  const int tid = threadIdx.x;
  const int lane = tid & 63;

  __shared__ float evf[64];
  __shared__ unsigned int pbuf[256];

  const _Float16* Ep = E + (size_t)bh * (NN * NM);

  h2 e[8][32];
#pragma unroll
  for (int i = 0; i < 8; ++i) {
    const uint4* src = (const uint4*)(Ep + (size_t)(tid + i * 256) * NM);
#pragma unroll
    for (int q = 0; q < 8; ++q) {
      uint4 v = src[q];
      e[i][q * 4 + 0] = __builtin_bit_cast(h2, v.x);
      e[i][q * 4 + 1] = __builtin_bit_cast(h2, v.y);
      e[i][q * 4 + 2] = __builtin_bit_cast(h2, v.z);
      e[i][q * 4 + 3] = __builtin_bit_cast(h2, v.w);
    }
  }

  float eu[8];
#pragma unroll
  for (int i = 0; i < 8; ++i) eu[i] = 1.f;
  if (tid < 64) evf[tid] = 1.f;
  __syncthreads();

#pragma unroll 1
  for (int it = 0; it < NITER; ++it) {
    // broadcast ev (f32 master in LDS) -> packed fp16 pairs
    h2 evpk[32];
#pragma unroll
    for (int q = 0; q < 16; ++q) {
      float4 v = ((const float4*)evf)[q];
      evpk[q * 2 + 0] = pkrtz(v.x, v.y);
      evpk[q * 2 + 1] = pkrtz(v.z, v.w);
    }
    // u-pass: S[n] = sum_m E*ev ; eu = (1/N)/(eu*S)
#pragma unroll
    for (int i = 0; i < 8; ++i) {
      float s = 0.f;
#pragma unroll
      for (int q = 0; q < 32; ++q) s = fdot2f(e[i][q], evpk[q], s);
      eu[i] = 4.8828125e-4f * __builtin_amdgcn_rcpf(eu[i] * s);
    }
    // v-pass local: T'[m] = sum_rows E * (eu*EUSCALE), packed fp16 per col-pair
    h2 eup[8];
#pragma unroll
    for (int i = 0; i < 8; ++i) {
      float es = eu[i] * EUSCALE;
      eup[i] = pkrtz(es, es);
    }
    h2 tp[32];
#pragma unroll
    for (int q = 0; q < 32; ++q) {
      h2 zz = {(_Float16)0.f, (_Float16)0.f};
      tp[q] = zz;
    }
#pragma unroll
    for (int i = 0; i < 8; ++i) {
#pragma unroll
      for (int q = 0; q < 32; ++q) tp[q] += e[i][q] * eup[i];
    }
    // register-halving butterfly: after 5 steps lane l holds wave-partial for
    // col-pair q = bitrev5(l&31); lanes l and l^32 hold the two half-sums.
#pragma unroll
    for (int k = 0; k < 5; ++k) {
      const int nn = 32 >> k;
      const bool up = (lane >> k) & 1;
#pragma unroll
      for (int p = 0; p < (nn >> 1); ++p) {
        h2 keep = up ? tp[p + (nn >> 1)] : tp[p];
        h2 send = up ? tp[p] : tp[p + (nn >> 1)];
        int rv = __shfl_xor(__builtin_bit_cast(int, send), 1 << k, 64);
        tp[p] = keep + __builtin_bit_cast(h2, rv);
      }
    }
    pbuf[tid] = __builtin_bit_cast(unsigned int, tp[0]);
    __syncthreads();
    if (tid < 32) {
      const int j = tid;
      const int rev = ((j & 1) << 4) | ((j & 2) << 2) | (j & 4) | ((j & 8) >> 2) | ((j & 16) >> 4);
      float T0 = 0.f, T1 = 0.f;
#pragma unroll
      for (int wq = 0; wq < 4; ++wq) {
        h2 a = __builtin_bit_cast(h2, pbuf[wq * 64 + rev]);
        h2 c = __builtin_bit_cast(h2, pbuf[wq * 64 + rev + 32]);
        T0 += (float)a[0] + (float)c[0];
        T1 += (float)a[1] + (float)c[1];
      }
      const float e0 = evf[2 * j], e1 = evf[2 * j + 1];
      // ev_new = 1/(ev_old*T) with T = T'/EUSCALE
      evf[2 * j]     = EUSCALE * __builtin_amdgcn_rcpf(e0 * T0);
      evf[2 * j + 1] = EUSCALE * __builtin_amdgcn_rcpf(e1 * T1);
    }
    __syncthreads();
  }

  // epilogue: P = E*eu*ev, write Pt[b][m][h][n] fp16 (coalesced over n=tid)
  float evv[64];
#pragma unroll
  for (int q = 0; q < 16; ++q) {
    float4 v = ((const float4*)evf)[q];
    evv[q * 4 + 0] = v.x; evv[q * 4 + 1] = v.y;
    evv[q * 4 + 2] = v.z; evv[q * 4 + 3] = v.w;
  }
  _Float16* Pb = Pt + ((size_t)(b * 256 + h)) * NN;
#pragma unroll
  for (int c = 0; c < 64; ++c) {
    const float evc = evv[c];
    _Float16* Pc = Pb + (size_t)c * 4 * NN;
#pragma unroll
    for (int i = 0; i < 8; ++i) {
      const int q = c >> 1;
      const float ee = (c & 1) ? (float)e[i][q][1] : (float)e[i][q][0];
      Pc[tid + i * 256] = (_Float16)(ee * eu[i] * evc);
    }
  }
}

// ------------------------------------------------------------- k3: out GEMM
// out[b][row][d] = sum_n Pt[b-row][n] * xT[b][d][n]; row=(m*4+h), f32 out.
__global__ __launch_bounds__(512) void k3_out(const _Float16* __restrict__ Pt,
                                              const _Float16* __restrict__ xT,
                                              float* __restrict__ out) {
  __shared__ _Float16 As[128][72];
  __shared__ _Float16 Bs[64][72];
  const int b = blockIdx.z;
  const int hf = blockIdx.y;
  const int dt = blockIdx.x;
  const int tid = threadIdx.x;
  const int lane = tid & 63;
  const int wv = tid >> 6;
  const int lrow = lane & 15;
  const int kq = lane >> 4;

  f4 acc[4];
#pragma unroll
  for (int i = 0; i < 4; ++i) acc[i] = (f4){0.f, 0.f, 0.f, 0.f};

  const int ar = tid >> 2, ac = (tid & 3) * 16;
  const int brd = tid >> 3, bn = (tid & 7) * 8;
  const _Float16* asrc = Pt + ((size_t)(b * 256 + hf * 128 + ar) * NN + ac);
  const _Float16* bsrc = xT + ((size_t)(b * ND + dt * 64 + brd) * NN + bn);

  for (int kt = 0; kt < 32; ++kt) {
    const int k0 = kt * 64;
    h8 a0 = *(const h8*)(asrc + k0);
    h8 a1 = *(const h8*)(asrc + k0 + 8);
    h8 bv = *(const h8*)(bsrc + k0);
    *(h8*)&As[ar][ac] = a0;
    *(h8*)&As[ar][ac + 8] = a1;
    *(h8*)&Bs[brd][bn] = bv;
    __syncthreads();
#pragma unroll
    for (int s = 0; s < 2; ++s) {
      h8 af = *(const h8*)&As[wv * 16 + lrow][s * 32 + kq * 8];
#pragma unroll
      for (int cf = 0; cf < 4; ++cf) {
        h8 bf = *(const h8*)&Bs[cf * 16 + lrow][s * 32 + kq * 8];
        acc[cf] = __builtin_amdgcn_mfma_f32_16x16x32_f16(af, bf, acc[cf], 0, 0, 0);
      }
    }
    __syncthreads();
  }
#pragma unroll
  for (int cf = 0; cf < 4; ++cf) {
    const int d = dt * 64 + cf * 16 + lrow;
#pragma unroll
    for (int j = 0; j < 4; ++j) {
      const int row = hf * 128 + wv * 16 + kq * 4 + j;
      out[(size_t)(b * 256 + row) * ND + d] = acc[cf][j];
    }
  }
}

// ---------------------------------------------------------------- launcher
extern "C" void kernel_launch(void* const* d_in, const int* in_sizes, int n_in,
                              void* d_out, int out_size, void* d_ws, size_t ws_size,
                              hipStream_t stream) {
  const float* x = (const float*)d_in[0];
  const float* w = (const float*)d_in[1];
  float* out = (float*)d_out;
  char* ws = (char*)d_ws;
  // ws layout (64 MiB total):
  //   xT : 16*512*2048 fp16 = 33,554,432 B
  //   E  : 16*4*2048*64 fp16 = 16,777,216 B
  //   Pt : 16*64*4*2048 fp16 = 16,777,216 B
  _Float16* xT = (_Float16*)ws;
  _Float16* E  = (_Float16*)(ws + (size_t)33554432);
  _Float16* Pt = (_Float16*)(ws + (size_t)50331648);

  k0_xt<<<dim3(32, 8, NB), 256, 0, stream>>>(x, xT);
  k1_buildE<<<dim3(16, NB), 512, 0, stream>>>(x, w, E);
  k2_sinkhorn<<<dim3(64), 256, 0, stream>>>(E, Pt);
  k3_out<<<dim3(8, 2, NB), 512, 0, stream>>>(Pt, xT, out);
}

// Round 2
// 184.513 us; speedup vs baseline: 1.1059x; 1.1059x over previous
//
#include <hip/hip_runtime.h>
#include <hip/hip_fp16.h>

// OTK (optimal-transport kernel attention) for MI355X.
// Pipeline:
//   k0: xT[b][d][n] = fp16(x)            (transpose for k3 B-operand)
//   k1: E[b][h][n][m] = exp(-10*C*pf)    (fp16 MFMA GEMM + fused epilogue)
//   k2: exp-domain Sinkhorn, E register-resident, 1024 thr/block (2 rows/thr),
//       writes Pt[b][m][h][n] = P transposed, fp16
//   k3: out[b][m*4+h][d] = Pt @ x        (fp16 MFMA GEMM)
// Identity used: lse_m(K+u+v) = u + lse_m(K+v)  =>  plain Sinkhorn on E=exp(K):
//   eu <- (1/N)/(eu*(E ev));  ev <- 1/(ev*(E^T eu));  P = E*eu*ev

typedef _Float16 h2 __attribute__((ext_vector_type(2)));
typedef _Float16 h8 __attribute__((ext_vector_type(8)));
typedef float f4 __attribute__((ext_vector_type(4)));

#define NB 16
#define NN 2048
#define ND 512
#define NH 4
#define NM 64
#define NITER 30
#define EUSCALE 8.0f   // keeps fp16(eu*EUSCALE) in normal range (eu >= ~1e-5)

static __device__ __forceinline__ float fdot2f(h2 a, h2 b, float c) {
#if __has_builtin(__builtin_amdgcn_fdot2)
  return __builtin_amdgcn_fdot2(a, b, c, false);
#else
  return (float)a[0] * (float)b[0] + (float)a[1] * (float)b[1] + c;
#endif
}

static __device__ __forceinline__ h2 pkrtz(float a, float b) {
  return __builtin_bit_cast(h2, __builtin_amdgcn_cvt_pkrtz(a, b));
}

static __device__ __forceinline__ h8 pack8(float4 a, float4 b) {
  h8 r;
  r[0] = (_Float16)a.x; r[1] = (_Float16)a.y; r[2] = (_Float16)a.z; r[3] = (_Float16)a.w;
  r[4] = (_Float16)b.x; r[5] = (_Float16)b.y; r[6] = (_Float16)b.z; r[7] = (_Float16)b.w;
  return r;
}

static __device__ __forceinline__ float sq4(float4 a) {
  return a.x * a.x + a.y * a.y + a.z * a.z + a.w * a.w;
}

// ---------------------------------------------------------------- k0: x -> xT
// 64x64 tiles through LDS (pad 65 -> 2-way max bank conflict both sides).
__global__ __launch_bounds__(256) void k0_xt(const float* __restrict__ x,
                                             _Float16* __restrict__ xT) {
  __shared__ float tile[64][65];
  const int b = blockIdx.z;
  const int n0 = blockIdx.x * 64;
  const int d0 = blockIdx.y * 64;
  const int t = threadIdx.x;
  const int nr = t >> 2;
  const int ds = (t & 3) * 16;
  const float4* src = (const float4*)(x + ((size_t)(b * NN + n0 + nr) * ND + d0 + ds));
  float4 v0 = src[0], v1 = src[1], v2 = src[2], v3 = src[3];
  float vals[16] = {v0.x, v0.y, v0.z, v0.w, v1.x, v1.y, v1.z, v1.w,
                    v2.x, v2.y, v2.z, v2.w, v3.x, v3.y, v3.z, v3.w};
#pragma unroll
  for (int j = 0; j < 16; ++j) tile[ds + j][nr] = vals[j];
  __syncthreads();
  const int dr = t >> 2;
  const int ns = (t & 3) * 16;
  h8 o0, o1;
#pragma unroll
  for (int j = 0; j < 8; ++j) o0[j] = (_Float16)tile[dr][ns + j];
#pragma unroll
  for (int j = 0; j < 8; ++j) o1[j] = (_Float16)tile[dr][ns + 8 + j];
  _Float16* dst = xT + ((size_t)(b * ND + d0 + dr) * NN + n0 + ns);
  *(h8*)dst = o0;
  *(h8*)(dst + 8) = o1;
}

// ------------------------------------------------------------- k1: build E
// Per block: n-tile of 128 x all 4 heads (256 cols), K=512, fp16 MFMA.
// x2/w2 accumulated during staging (each element staged exactly once).
__global__ __launch_bounds__(512) void k1_buildE(const float* __restrict__ x,
                                                 const float* __restrict__ w,
                                                 _Float16* __restrict__ E) {
  __shared__ _Float16 Ah[128][72];   // +8 pad: balanced banks for b128 reads
  __shared__ _Float16 Bh[256][72];
  __shared__ float x2s[128][4];
  __shared__ float w2s[256][2];
  __shared__ float x2r[128];
  __shared__ float w2r[256];

  const int b = blockIdx.y;
  const int n0 = blockIdx.x * 128;
  const int tid = threadIdx.x;
  const int lane = tid & 63;
  const int wv = tid >> 6;        // 8 waves, 16 n-rows each
  const int lrow = lane & 15;
  const int kq = lane >> 4;

  f4 acc[16];
#pragma unroll
  for (int i = 0; i < 16; ++i) acc[i] = (f4){0.f, 0.f, 0.f, 0.f};

  const int ar = tid >> 2, ac = (tid & 3) * 16;
  const int br = tid >> 1, bc = (tid & 1) * 32;
  const float* xsrc = x + ((size_t)(b * NN + n0 + ar) * ND + ac);
  const float* wsrc = w + ((size_t)br * ND + bc);
  float x2p = 0.f, w2p = 0.f;

  for (int kt = 0; kt < 8; ++kt) {
    {
      const float4* s4 = (const float4*)(xsrc + kt * 64);
      float4 a0 = s4[0], a1 = s4[1], a2 = s4[2], a3 = s4[3];
      x2p += sq4(a0) + sq4(a1) + sq4(a2) + sq4(a3);
      *(h8*)&Ah[ar][ac] = pack8(a0, a1);
      *(h8*)&Ah[ar][ac + 8] = pack8(a2, a3);
    }
    {
      const float4* s4 = (const float4*)(wsrc + kt * 64);
      float4 u0 = s4[0], u1 = s4[1], u2 = s4[2], u3 = s4[3];
      float4 u4 = s4[4], u5 = s4[5], u6 = s4[6], u7 = s4[7];
      w2p += sq4(u0) + sq4(u1) + sq4(u2) + sq4(u3)
           + sq4(u4) + sq4(u5) + sq4(u6) + sq4(u7);
      *(h8*)&Bh[br][bc] = pack8(u0, u1);
      *(h8*)&Bh[br][bc + 8] = pack8(u2, u3);
      *(h8*)&Bh[br][bc + 16] = pack8(u4, u5);
      *(h8*)&Bh[br][bc + 24] = pack8(u6, u7);
    }
    __syncthreads();
#pragma unroll
    for (int s = 0; s < 2; ++s) {
      h8 af = *(const h8*)&Ah[wv * 16 + lrow][s * 32 + kq * 8];
#pragma unroll
      for (int cf = 0; cf < 16; ++cf) {
        h8 bf = *(const h8*)&Bh[cf * 16 + lrow][s * 32 + kq * 8];
        acc[cf] = __builtin_amdgcn_mfma_f32_16x16x32_f16(af, bf, acc[cf], 0, 0, 0);
      }
    }
    __syncthreads();
  }

  x2s[ar][tid & 3] = x2p;
  w2s[br][tid & 1] = w2p;
  __syncthreads();
  if (tid < 128) {
    x2r[tid] = x2s[tid][0] + x2s[tid][1] + x2s[tid][2] + x2s[tid][3];
  } else if (tid < 384) {
    const int r = tid - 128;
    w2r[r] = w2s[r][0] + w2s[r][1];
  }
  __syncthreads();

#pragma unroll
  for (int cf = 0; cf < 16; ++cf) {
    const int mg = cf * 16 + lrow;
    const int hh = mg >> 6;
    const int m = mg & 63;
    const float w2v = w2r[mg];
    const float bm = (float)m * (1.0f / 64.0f);
    _Float16* Eb = E + ((size_t)(b * NH + hh) * NN) * NM;
#pragma unroll
    for (int j = 0; j < 4; ++j) {
      const int nl = wv * 16 + kq * 4 + j;   // C/D: row=(lane>>4)*4+reg
      const int n = n0 + nl;
      const float c2 = x2r[nl] + w2v - 2.0f * acc[cf][j];
      const float Cd = sqrtf(fmaxf(c2, 0.0f));
      const float tt = (float)n * (1.0f / 2048.0f) - bm;
      const float pf = __expf(-100.0f * tt * tt);
      const float Ev = __expf(-10.0f * Cd * pf);   // K = (-C/eps)*pf, eps=0.1
      Eb[(size_t)n * NM + m] = (_Float16)Ev;
    }
  }
}

// ------------------------------------------------------------ k2: Sinkhorn
// One block per (b,h). 1024 threads x 2 adjacent rows each; E fp16 in
// registers (64 VGPR), 16 waves/CU = 4 waves/SIMD for latency hiding.
// Per iter: row sums via v_dot2_f32_f16 (4 chains for ILP), col sums via
// v_pk_fma_f16 + register-halving butterfly + 16-wave LDS combine.
__global__ __launch_bounds__(1024) void k2_sinkhorn(const _Float16* __restrict__ E,
                                                    _Float16* __restrict__ Pt) {
  const int bh = blockIdx.x;
  const int b = bh >> 2, h = bh & 3;
  const int tid = threadIdx.x;
  const int lane = tid & 63;

  __shared__ float evf[64];
  __shared__ __align__(16) h2 evh[32];
  __shared__ unsigned int pbuf[1024];

  const _Float16* Ep = E + (size_t)bh * (NN * NM);

  // rows 2*tid and 2*tid+1 (adjacent: packs the Pt epilogue into dword stores)
  h2 e[2][32];
#pragma unroll
  for (int i = 0; i < 2; ++i) {
    const uint4* src = (const uint4*)(Ep + (size_t)(2 * tid + i) * NM);
#pragma unroll
    for (int q = 0; q < 8; ++q) {
      uint4 v = src[q];
      e[i][q * 4 + 0] = __builtin_bit_cast(h2, v.x);
      e[i][q * 4 + 1] = __builtin_bit_cast(h2, v.y);
      e[i][q * 4 + 2] = __builtin_bit_cast(h2, v.z);
      e[i][q * 4 + 3] = __builtin_bit_cast(h2, v.w);
    }
  }

  float eu[2] = {1.f, 1.f};
  if (tid < 64) evf[tid] = 1.f;
  if (tid < 32) evh[tid] = pkrtz(1.f, 1.f);
  __syncthreads();

#pragma unroll 1
  for (int it = 0; it < NITER; ++it) {
    // broadcast ev (fp16-packed master in LDS)
    h2 evr[32];
    {
      const uint4* ev4 = (const uint4*)evh;
#pragma unroll
      for (int q8 = 0; q8 < 8; ++q8) {
        uint4 v = ev4[q8];
        evr[q8 * 4 + 0] = __builtin_bit_cast(h2, v.x);
        evr[q8 * 4 + 1] = __builtin_bit_cast(h2, v.y);
        evr[q8 * 4 + 2] = __builtin_bit_cast(h2, v.z);
        evr[q8 * 4 + 3] = __builtin_bit_cast(h2, v.w);
      }
    }
    // u-pass: S[n] = sum_m E*ev ; eu = (1/N)/(eu*S).  4 chains for ILP.
    float s0a = 0.f, s0b = 0.f, s1a = 0.f, s1b = 0.f;
#pragma unroll
    for (int q = 0; q < 16; ++q) {
      s0a = fdot2f(e[0][q], evr[q], s0a);
      s1a = fdot2f(e[1][q], evr[q], s1a);
    }
#pragma unroll
    for (int q = 16; q < 32; ++q) {
      s0b = fdot2f(e[0][q], evr[q], s0b);
      s1b = fdot2f(e[1][q], evr[q], s1b);
    }
    eu[0] = 4.8828125e-4f * __builtin_amdgcn_rcpf(eu[0] * (s0a + s0b));
    eu[1] = 4.8828125e-4f * __builtin_amdgcn_rcpf(eu[1] * (s1a + s1b));
    // v-pass local: T'[m] = sum_rows E * (eu*EUSCALE)
    const float es0 = eu[0] * EUSCALE, es1 = eu[1] * EUSCALE;
    const h2 eup0 = pkrtz(es0, es0);
    const h2 eup1 = pkrtz(es1, es1);
    h2 tp[32];
#pragma unroll
    for (int q = 0; q < 32; ++q) {
      tp[q] = e[0][q] * eup0 + e[1][q] * eup1;
    }
    // register-halving butterfly: after 5 steps lane l holds wave-partial for
    // col-pair q = bitrev5(l&31); lanes l and l^32 hold the two half-sums.
#pragma unroll
    for (int k = 0; k < 5; ++k) {
      const int nn = 32 >> k;
      const bool up = (lane >> k) & 1;
#pragma unroll
      for (int p = 0; p < (nn >> 1); ++p) {
        h2 keep = up ? tp[p + (nn >> 1)] : tp[p];
        h2 send = up ? tp[p] : tp[p + (nn >> 1)];
        int rv = __shfl_xor(__builtin_bit_cast(int, send), 1 << k, 64);
        tp[p] = keep + __builtin_bit_cast(h2, rv);
      }
    }
    pbuf[tid] = __builtin_bit_cast(unsigned int, tp[0]);
    __syncthreads();
    if (tid < 32) {
      const int j = tid;
      const int rev = ((j & 1) << 4) | ((j & 2) << 2) | (j & 4) | ((j & 8) >> 2) | ((j & 16) >> 4);
      float T0 = 0.f, T1 = 0.f;
#pragma unroll
      for (int wq = 0; wq < 16; ++wq) {
        h2 a = __builtin_bit_cast(h2, pbuf[wq * 64 + rev]);
        h2 c = __builtin_bit_cast(h2, pbuf[wq * 64 + rev + 32]);
        T0 += (float)a[0] + (float)c[0];
        T1 += (float)a[1] + (float)c[1];
      }
      const float e0 = evf[2 * j], e1 = evf[2 * j + 1];
      // ev_new = 1/(ev_old*T) with T = T'/EUSCALE
      const float n0 = EUSCALE * __builtin_amdgcn_rcpf(e0 * T0);
      const float n1 = EUSCALE * __builtin_amdgcn_rcpf(e1 * T1);
      evf[2 * j] = n0;
      evf[2 * j + 1] = n1;
      evh[j] = pkrtz(n0, n1);
    }
    __syncthreads();
  }

  // epilogue: P = E*eu*ev, Pt[b][m][h][n] fp16; rows 2t,2t+1 pack to dwords.
  _Float16* Pb = Pt + ((size_t)(b * 256 + h)) * NN;
#pragma unroll
  for (int q = 0; q < 32; ++q) {
    const float ev0 = evf[2 * q];
    const float ev1 = evf[2 * q + 1];
    const float a00 = (float)e[0][q][0] * eu[0] * ev0;   // row 2t,   col 2q
    const float a10 = (float)e[1][q][0] * eu[1] * ev0;   // row 2t+1, col 2q
    const float a01 = (float)e[0][q][1] * eu[0] * ev1;   // row 2t,   col 2q+1
    const float a11 = (float)e[1][q][1] * eu[1] * ev1;   // row 2t+1, col 2q+1
    *(h2*)(Pb + (size_t)(2 * q) * 4 * NN + 2 * tid) = pkrtz(a00, a10);
    *(h2*)(Pb + (size_t)(2 * q + 1) * 4 * NN + 2 * tid) = pkrtz(a01, a11);
  }
}

// ------------------------------------------------------------- k3: out GEMM
// out[b][row][d] = sum_n Pt[b-row][n] * xT[b][d][n]; row=(m*4+h), f32 out.
__global__ __launch_bounds__(512) void k3_out(const _Float16* __restrict__ Pt,
                                              const _Float16* __restrict__ xT,
                                              float* __restrict__ out) {
  __shared__ _Float16 As[128][72];
  __shared__ _Float16 Bs[64][72];
  const int b = blockIdx.z;
  const int hf = blockIdx.y;
  const int dt = blockIdx.x;
  const int tid = threadIdx.x;
  const int lane = tid & 63;
  const int wv = tid >> 6;
  const int lrow = lane & 15;
  const int kq = lane >> 4;

  f4 acc[4];
#pragma unroll
  for (int i = 0; i < 4; ++i) acc[i] = (f4){0.f, 0.f, 0.f, 0.f};

  const int ar = tid >> 2, ac = (tid & 3) * 16;
  const int brd = tid >> 3, bn = (tid & 7) * 8;
  const _Float16* asrc = Pt + ((size_t)(b * 256 + hf * 128 + ar) * NN + ac);
  const _Float16* bsrc = xT + ((size_t)(b * ND + dt * 64 + brd) * NN + bn);

  for (int kt = 0; kt < 32; ++kt) {
    const int k0 = kt * 64;
    h8 a0 = *(const h8*)(asrc + k0);
    h8 a1 = *(const h8*)(asrc + k0 + 8);
    h8 bv = *(const h8*)(bsrc + k0);
    *(h8*)&As[ar][ac] = a0;
    *(h8*)&As[ar][ac + 8] = a1;
    *(h8*)&Bs[brd][bn] = bv;
    __syncthreads();
#pragma unroll
    for (int s = 0; s < 2; ++s) {
      h8 af = *(const h8*)&As[wv * 16 + lrow][s * 32 + kq * 8];
#pragma unroll
      for (int cf = 0; cf < 4; ++cf) {
        h8 bf = *(const h8*)&Bs[cf * 16 + lrow][s * 32 + kq * 8];
        acc[cf] = __builtin_amdgcn_mfma_f32_16x16x32_f16(af, bf, acc[cf], 0, 0, 0);
      }
    }
    __syncthreads();
  }
#pragma unroll
  for (int cf = 0; cf < 4; ++cf) {
    const int d = dt * 64 + cf * 16 + lrow;
#pragma unroll
    for (int j = 0; j < 4; ++j) {
      const int row = hf * 128 + wv * 16 + kq * 4 + j;
      out[(size_t)(b * 256 + row) * ND + d] = acc[cf][j];
    }
  }
}

// ---------------------------------------------------------------- launcher
extern "C" void kernel_launch(void* const* d_in, const int* in_sizes, int n_in,
                              void* d_out, int out_size, void* d_ws, size_t ws_size,
                              hipStream_t stream) {
  const float* x = (const float*)d_in[0];
  const float* w = (const float*)d_in[1];
  float* out = (float*)d_out;
  char* ws = (char*)d_ws;
  // ws layout (64 MiB total):
  //   xT : 16*512*2048 fp16 = 33,554,432 B
  //   E  : 16*4*2048*64 fp16 = 16,777,216 B
  //   Pt : 16*64*4*2048 fp16 = 16,777,216 B
  _Float16* xT = (_Float16*)ws;
  _Float16* E  = (_Float16*)(ws + (size_t)33554432);
  _Float16* Pt = (_Float16*)(ws + (size_t)50331648);

  k0_xt<<<dim3(32, 8, NB), 256, 0, stream>>>(x, xT);
  k1_buildE<<<dim3(16, NB), 512, 0, stream>>>(x, w, E);
  k2_sinkhorn<<<dim3(64), 1024, 0, stream>>>(E, Pt);
  k3_out<<<dim3(8, 2, NB), 512, 0, stream>>>(Pt, xT, out);
}

// Round 3
// 172.112 us; speedup vs baseline: 1.1855x; 1.0721x over previous
//
#include <hip/hip_runtime.h>
#include <hip/hip_fp16.h>

// OTK (optimal-transport kernel attention) for MI355X.
// Pipeline:
//   k0: xT[b][d][n] = fp16(x)            (transpose for k3 B-operand)
//   k1: E[b][h][n][m] = exp(-10*C*pf)    (fp16 MFMA GEMM + fused epilogue)
//   k2: exp-domain Sinkhorn, E register-resident, 512 thr/block (4 rows/thr),
//       writes Pt[b][m][h][n] = P transposed, fp16
//   k3: out[b][m*4+h][d] = Pt @ x        (fp16 MFMA GEMM)
// Identity used: lse_m(K+u+v) = u + lse_m(K+v)  =>  plain Sinkhorn on E=exp(K):
//   eu <- (1/N)/(eu*(E ev));  ev <- 1/(ev*(E^T eu));  P = E*eu*ev
//
// Round-2 lesson: 1024-thr blocks cap VGPR at 128 -> compiler rematerialized
// the E loads (VGPR_Count=56) and re-read E from L2 every pass. 512-thr
// blocks (launch_bounds(512,2) -> 256-VGPR cap) give the allocator slack to
// keep e[4][32] (128 VGPRs) truly resident.

typedef _Float16 h2 __attribute__((ext_vector_type(2)));
typedef _Float16 h8 __attribute__((ext_vector_type(8)));
typedef float f4 __attribute__((ext_vector_type(4)));

#define NB 16
#define NN 2048
#define ND 512
#define NH 4
#define NM 64
#define NITER 30
#define EUSCALE 8.0f   // keeps fp16(eu*EUSCALE) in normal range (eu >= ~1e-5)

static __device__ __forceinline__ float fdot2f(h2 a, h2 b, float c) {
#if __has_builtin(__builtin_amdgcn_fdot2)
  return __builtin_amdgcn_fdot2(a, b, c, false);
#else
  return (float)a[0] * (float)b[0] + (float)a[1] * (float)b[1] + c;
#endif
}

static __device__ __forceinline__ h2 pkrtz(float a, float b) {
  return __builtin_bit_cast(h2, __builtin_amdgcn_cvt_pkrtz(a, b));
}

static __device__ __forceinline__ h8 pack8(float4 a, float4 b) {
  h8 r;
  r[0] = (_Float16)a.x; r[1] = (_Float16)a.y; r[2] = (_Float16)a.z; r[3] = (_Float16)a.w;
  r[4] = (_Float16)b.x; r[5] = (_Float16)b.y; r[6] = (_Float16)b.z; r[7] = (_Float16)b.w;
  return r;
}

static __device__ __forceinline__ float sq4(float4 a) {
  return a.x * a.x + a.y * a.y + a.z * a.z + a.w * a.w;
}

// ---------------------------------------------------------------- k0: x -> xT
// 64x64 tiles through LDS (pad 65 -> 2-way max bank conflict both sides).
__global__ __launch_bounds__(256) void k0_xt(const float* __restrict__ x,
                                             _Float16* __restrict__ xT) {
  __shared__ float tile[64][65];
  const int b = blockIdx.z;
  const int n0 = blockIdx.x * 64;
  const int d0 = blockIdx.y * 64;
  const int t = threadIdx.x;
  const int nr = t >> 2;
  const int ds = (t & 3) * 16;
  const float4* src = (const float4*)(x + ((size_t)(b * NN + n0 + nr) * ND + d0 + ds));
  float4 v0 = src[0], v1 = src[1], v2 = src[2], v3 = src[3];
  float vals[16] = {v0.x, v0.y, v0.z, v0.w, v1.x, v1.y, v1.z, v1.w,
                    v2.x, v2.y, v2.z, v2.w, v3.x, v3.y, v3.z, v3.w};
#pragma unroll
  for (int j = 0; j < 16; ++j) tile[ds + j][nr] = vals[j];
  __syncthreads();
  const int dr = t >> 2;
  const int ns = (t & 3) * 16;
  h8 o0, o1;
#pragma unroll
  for (int j = 0; j < 8; ++j) o0[j] = (_Float16)tile[dr][ns + j];
#pragma unroll
  for (int j = 0; j < 8; ++j) o1[j] = (_Float16)tile[dr][ns + 8 + j];
  _Float16* dst = xT + ((size_t)(b * ND + d0 + dr) * NN + n0 + ns);
  *(h8*)dst = o0;
  *(h8*)(dst + 8) = o1;
}

// ------------------------------------------------------------- k1: build E
// Per block: n-tile of 128 x all 4 heads (256 cols), K=512, fp16 MFMA.
// x2/w2 accumulated during staging (each element staged exactly once).
__global__ __launch_bounds__(512) void k1_buildE(const float* __restrict__ x,
                                                 const float* __restrict__ w,
                                                 _Float16* __restrict__ E) {
  __shared__ _Float16 Ah[128][72];   // +8 pad: balanced banks for b128 reads
  __shared__ _Float16 Bh[256][72];
  __shared__ float x2s[128][4];
  __shared__ float w2s[256][2];
  __shared__ float x2r[128];
  __shared__ float w2r[256];

  const int b = blockIdx.y;
  const int n0 = blockIdx.x * 128;
  const int tid = threadIdx.x;
  const int lane = tid & 63;
  const int wv = tid >> 6;        // 8 waves, 16 n-rows each
  const int lrow = lane & 15;
  const int kq = lane >> 4;

  f4 acc[16];
#pragma unroll
  for (int i = 0; i < 16; ++i) acc[i] = (f4){0.f, 0.f, 0.f, 0.f};

  const int ar = tid >> 2, ac = (tid & 3) * 16;
  const int br = tid >> 1, bc = (tid & 1) * 32;
  const float* xsrc = x + ((size_t)(b * NN + n0 + ar) * ND + ac);
  const float* wsrc = w + ((size_t)br * ND + bc);
  float x2p = 0.f, w2p = 0.f;

  for (int kt = 0; kt < 8; ++kt) {
    {
      const float4* s4 = (const float4*)(xsrc + kt * 64);
      float4 a0 = s4[0], a1 = s4[1], a2 = s4[2], a3 = s4[3];
      x2p += sq4(a0) + sq4(a1) + sq4(a2) + sq4(a3);
      *(h8*)&Ah[ar][ac] = pack8(a0, a1);
      *(h8*)&Ah[ar][ac + 8] = pack8(a2, a3);
    }
    {
      const float4* s4 = (const float4*)(wsrc + kt * 64);
      float4 u0 = s4[0], u1 = s4[1], u2 = s4[2], u3 = s4[3];
      float4 u4 = s4[4], u5 = s4[5], u6 = s4[6], u7 = s4[7];
      w2p += sq4(u0) + sq4(u1) + sq4(u2) + sq4(u3)
           + sq4(u4) + sq4(u5) + sq4(u6) + sq4(u7);
      *(h8*)&Bh[br][bc] = pack8(u0, u1);
      *(h8*)&Bh[br][bc + 8] = pack8(u2, u3);
      *(h8*)&Bh[br][bc + 16] = pack8(u4, u5);
      *(h8*)&Bh[br][bc + 24] = pack8(u6, u7);
    }
    __syncthreads();
#pragma unroll
    for (int s = 0; s < 2; ++s) {
      h8 af = *(const h8*)&Ah[wv * 16 + lrow][s * 32 + kq * 8];
#pragma unroll
      for (int cf = 0; cf < 16; ++cf) {
        h8 bf = *(const h8*)&Bh[cf * 16 + lrow][s * 32 + kq * 8];
        acc[cf] = __builtin_amdgcn_mfma_f32_16x16x32_f16(af, bf, acc[cf], 0, 0, 0);
      }
    }
    __syncthreads();
  }

  x2s[ar][tid & 3] = x2p;
  w2s[br][tid & 1] = w2p;
  __syncthreads();
  if (tid < 128) {
    x2r[tid] = x2s[tid][0] + x2s[tid][1] + x2s[tid][2] + x2s[tid][3];
  } else if (tid < 384) {
    const int r = tid - 128;
    w2r[r] = w2s[r][0] + w2s[r][1];
  }
  __syncthreads();

#pragma unroll
  for (int cf = 0; cf < 16; ++cf) {
    const int mg = cf * 16 + lrow;
    const int hh = mg >> 6;
    const int m = mg & 63;
    const float w2v = w2r[mg];
    const float bm = (float)m * (1.0f / 64.0f);
    _Float16* Eb = E + ((size_t)(b * NH + hh) * NN) * NM;
#pragma unroll
    for (int j = 0; j < 4; ++j) {
      const int nl = wv * 16 + kq * 4 + j;   // C/D: row=(lane>>4)*4+reg
      const int n = n0 + nl;
      const float c2 = x2r[nl] + w2v - 2.0f * acc[cf][j];
      const float Cd = sqrtf(fmaxf(c2, 0.0f));
      const float tt = (float)n * (1.0f / 2048.0f) - bm;
      const float pf = __expf(-100.0f * tt * tt);
      const float Ev = __expf(-10.0f * Cd * pf);   // K = (-C/eps)*pf, eps=0.1
      Eb[(size_t)n * NM + m] = (_Float16)Ev;
    }
  }
}

// ------------------------------------------------------------ k2: Sinkhorn
// One block per (b,h). 512 threads x 4 adjacent rows each; E fp16 truly in
// registers (128 VGPR for e; 256-VGPR class => no remat pressure).
// Per iter: row sums via v_dot2_f32_f16 (8 chains for ILP), col sums via
// v_pk_fma_f16 + register-halving butterfly + 8-wave LDS combine.
__global__ __launch_bounds__(512, 2) void k2_sinkhorn(const _Float16* __restrict__ E,
                                                      _Float16* __restrict__ Pt) {
  const int bh = blockIdx.x;
  const int b = bh >> 2, h = bh & 3;
  const int tid = threadIdx.x;
  const int lane = tid & 63;

  __shared__ float evf[64];
  __shared__ __align__(16) h2 evh[32];
  __shared__ unsigned int pbuf[512];

  const _Float16* Ep = E + (size_t)bh * (NN * NM);

  // rows 4*tid .. 4*tid+3 (adjacent: packs the Pt epilogue into 8B stores)
  h2 e[4][32];
#pragma unroll
  for (int i = 0; i < 4; ++i) {
    const uint4* src = (const uint4*)(Ep + (size_t)(4 * tid + i) * NM);
#pragma unroll
    for (int q = 0; q < 8; ++q) {
      uint4 v = src[q];
      e[i][q * 4 + 0] = __builtin_bit_cast(h2, v.x);
      e[i][q * 4 + 1] = __builtin_bit_cast(h2, v.y);
      e[i][q * 4 + 2] = __builtin_bit_cast(h2, v.z);
      e[i][q * 4 + 3] = __builtin_bit_cast(h2, v.w);
    }
  }

  float eu[4] = {1.f, 1.f, 1.f, 1.f};
  if (tid < 64) evf[tid] = 1.f;
  if (tid < 32) evh[tid] = pkrtz(1.f, 1.f);
  __syncthreads();

#pragma unroll 1
  for (int it = 0; it < NITER; ++it) {
    // broadcast ev (fp16-packed master in LDS)
    h2 evr[32];
    {
      const uint4* ev4 = (const uint4*)evh;
#pragma unroll
      for (int q8 = 0; q8 < 8; ++q8) {
        uint4 v = ev4[q8];
        evr[q8 * 4 + 0] = __builtin_bit_cast(h2, v.x);
        evr[q8 * 4 + 1] = __builtin_bit_cast(h2, v.y);
        evr[q8 * 4 + 2] = __builtin_bit_cast(h2, v.z);
        evr[q8 * 4 + 3] = __builtin_bit_cast(h2, v.w);
      }
    }
    // u-pass: S[n] = sum_m E*ev ; eu = (1/N)/(eu*S).  8 chains for ILP.
    float sa[4] = {0.f, 0.f, 0.f, 0.f};
    float sb[4] = {0.f, 0.f, 0.f, 0.f};
#pragma unroll
    for (int q = 0; q < 16; ++q) {
#pragma unroll
      for (int i = 0; i < 4; ++i) sa[i] = fdot2f(e[i][q], evr[q], sa[i]);
    }
#pragma unroll
    for (int q = 16; q < 32; ++q) {
#pragma unroll
      for (int i = 0; i < 4; ++i) sb[i] = fdot2f(e[i][q], evr[q], sb[i]);
    }
#pragma unroll
    for (int i = 0; i < 4; ++i) {
      eu[i] = 4.8828125e-4f * __builtin_amdgcn_rcpf(eu[i] * (sa[i] + sb[i]));
    }
    // v-pass local: T'[m] = sum_rows E * (eu*EUSCALE)
    h2 eup[4];
#pragma unroll
    for (int i = 0; i < 4; ++i) {
      const float es = eu[i] * EUSCALE;
      eup[i] = pkrtz(es, es);
    }
    h2 tp[32];
#pragma unroll
    for (int q = 0; q < 32; ++q) {
      tp[q] = e[0][q] * eup[0] + e[1][q] * eup[1];
      tp[q] += e[2][q] * eup[2] + e[3][q] * eup[3];
    }
    // register-halving butterfly: after 5 steps lane l holds wave-partial for
    // col-pair q = bitrev5(l&31); lanes l and l^32 hold the two half-sums.
#pragma unroll
    for (int k = 0; k < 5; ++k) {
      const int nn = 32 >> k;
      const bool up = (lane >> k) & 1;
#pragma unroll
      for (int p = 0; p < (nn >> 1); ++p) {
        h2 keep = up ? tp[p + (nn >> 1)] : tp[p];
        h2 send = up ? tp[p] : tp[p + (nn >> 1)];
        int rv = __shfl_xor(__builtin_bit_cast(int, send), 1 << k, 64);
        tp[p] = keep + __builtin_bit_cast(h2, rv);
      }
    }
    pbuf[tid] = __builtin_bit_cast(unsigned int, tp[0]);
    __syncthreads();
    if (tid < 32) {
      const int j = tid;
      const int rev = ((j & 1) << 4) | ((j & 2) << 2) | (j & 4) | ((j & 8) >> 2) | ((j & 16) >> 4);
      float T0 = 0.f, T1 = 0.f;
#pragma unroll
      for (int wq = 0; wq < 8; ++wq) {
        h2 a = __builtin_bit_cast(h2, pbuf[wq * 64 + rev]);
        h2 c = __builtin_bit_cast(h2, pbuf[wq * 64 + rev + 32]);
        T0 += (float)a[0] + (float)c[0];
        T1 += (float)a[1] + (float)c[1];
      }
      const float e0 = evf[2 * j], e1 = evf[2 * j + 1];
      // ev_new = 1/(ev_old*T) with T = T'/EUSCALE
      const float n0 = EUSCALE * __builtin_amdgcn_rcpf(e0 * T0);
      const float n1 = EUSCALE * __builtin_amdgcn_rcpf(e1 * T1);
      evf[2 * j] = n0;
      evf[2 * j + 1] = n1;
      evh[j] = pkrtz(n0, n1);
    }
    __syncthreads();
  }

  // epilogue: P = E*eu*ev, Pt[b][m][h][n] fp16; rows 4t..4t+3 pack to 8B stores.
  _Float16* Pb = Pt + ((size_t)(b * 256 + h)) * NN;
#pragma unroll
  for (int q = 0; q < 32; ++q) {
    const float ev0 = evf[2 * q];
    const float ev1 = evf[2 * q + 1];
    float a0[4], a1[4];
#pragma unroll
    for (int i = 0; i < 4; ++i) {
      a0[i] = (float)e[i][q][0] * eu[i] * ev0;   // row 4t+i, col 2q
      a1[i] = (float)e[i][q][1] * eu[i] * ev1;   // row 4t+i, col 2q+1
    }
    uint2 st0, st1;
    st0.x = __builtin_bit_cast(unsigned int, pkrtz(a0[0], a0[1]));
    st0.y = __builtin_bit_cast(unsigned int, pkrtz(a0[2], a0[3]));
    st1.x = __builtin_bit_cast(unsigned int, pkrtz(a1[0], a1[1]));
    st1.y = __builtin_bit_cast(unsigned int, pkrtz(a1[2], a1[3]));
    *(uint2*)(Pb + (size_t)(2 * q) * 4 * NN + 4 * tid) = st0;
    *(uint2*)(Pb + (size_t)(2 * q + 1) * 4 * NN + 4 * tid) = st1;
  }
}

// ------------------------------------------------------------- k3: out GEMM
// out[b][row][d] = sum_n Pt[b-row][n] * xT[b][d][n]; row=(m*4+h), f32 out.
__global__ __launch_bounds__(512) void k3_out(const _Float16* __restrict__ Pt,
                                              const _Float16* __restrict__ xT,
                                              float* __restrict__ out) {
  __shared__ _Float16 As[128][72];
  __shared__ _Float16 Bs[64][72];
  const int b = blockIdx.z;
  const int hf = blockIdx.y;
  const int dt = blockIdx.x;
  const int tid = threadIdx.x;
  const int lane = tid & 63;
  const int wv = tid >> 6;
  const int lrow = lane & 15;
  const int kq = lane >> 4;

  f4 acc[4];
#pragma unroll
  for (int i = 0; i < 4; ++i) acc[i] = (f4){0.f, 0.f, 0.f, 0.f};

  const int ar = tid >> 2, ac = (tid & 3) * 16;
  const int brd = tid >> 3, bn = (tid & 7) * 8;
  const _Float16* asrc = Pt + ((size_t)(b * 256 + hf * 128 + ar) * NN + ac);
  const _Float16* bsrc = xT + ((size_t)(b * ND + dt * 64 + brd) * NN + bn);

  for (int kt = 0; kt < 32; ++kt) {
    const int k0 = kt * 64;
    h8 a0 = *(const h8*)(asrc + k0);
    h8 a1 = *(const h8*)(asrc + k0 + 8);
    h8 bv = *(const h8*)(bsrc + k0);
    *(h8*)&As[ar][ac] = a0;
    *(h8*)&As[ar][ac + 8] = a1;
    *(h8*)&Bs[brd][bn] = bv;
    __syncthreads();
#pragma unroll
    for (int s = 0; s < 2; ++s) {
      h8 af = *(const h8*)&As[wv * 16 + lrow][s * 32 + kq * 8];
#pragma unroll
      for (int cf = 0; cf < 4; ++cf) {
        h8 bf = *(const h8*)&Bs[cf * 16 + lrow][s * 32 + kq * 8];
        acc[cf] = __builtin_amdgcn_mfma_f32_16x16x32_f16(af, bf, acc[cf], 0, 0, 0);
      }
    }
    __syncthreads();
  }
#pragma unroll
  for (int cf = 0; cf < 4; ++cf) {
    const int d = dt * 64 + cf * 16 + lrow;
#pragma unroll
    for (int j = 0; j < 4; ++j) {
      const int row = hf * 128 + wv * 16 + kq * 4 + j;
      out[(size_t)(b * 256 + row) * ND + d] = acc[cf][j];
    }
  }
}

// ---------------------------------------------------------------- launcher
extern "C" void kernel_launch(void* const* d_in, const int* in_sizes, int n_in,
                              void* d_out, int out_size, void* d_ws, size_t ws_size,
                              hipStream_t stream) {
  const float* x = (const float*)d_in[0];
  const float* w = (const float*)d_in[1];
  float* out = (float*)d_out;
  char* ws = (char*)d_ws;
  // ws layout (64 MiB total):
  //   xT : 16*512*2048 fp16 = 33,554,432 B
  //   E  : 16*4*2048*64 fp16 = 16,777,216 B
  //   Pt : 16*64*4*2048 fp16 = 16,777,216 B
  _Float16* xT = (_Float16*)ws;
  _Float16* E  = (_Float16*)(ws + (size_t)33554432);
  _Float16* Pt = (_Float16*)(ws + (size_t)50331648);

  k0_xt<<<dim3(32, 8, NB), 256, 0, stream>>>(x, xT);
  k1_buildE<<<dim3(16, NB), 512, 0, stream>>>(x, w, E);
  k2_sinkhorn<<<dim3(64), 512, 0, stream>>>(E, Pt);
  k3_out<<<dim3(8, 2, NB), 512, 0, stream>>>(Pt, xT, out);
}